// Round 6
// baseline (8036.135 us; speedup 1.0000x reference)
//
#include <hip/hip_runtime.h>

// LSTM decoder w/ Bahdanau attention, MI355X.
// Persistent grid-synchronized kernel, R12: R7 structure (256 blocks x 512
// threads, 1 block/CU, 4 independent groups of 64 blocks / 16 batches,
// per-group flag barriers) + q-quarter exchange WITHOUT register caching:
//   each (b,qt) block computes its 64 q-rows reading only its 64KB Wq2
//   slice from L2 (was: every block reads full 256KB -> 64MB/step chip),
//   publishes via qex + qflag 4-party exchange; exchange RT hides under
//   out(t-1) + zero-ahead stores. Zero added persistent VGPRs (R11 lesson).
// TWO per-group barriers per step:
//   PA (block=(batch b, quarter qt)): stage h[b](fp32)->LDS; prestage x/h
//       A-tile rows; q-slice (L2 weights) -> qex exchange; out(t-1) 16 rows;
//       energies tanh(q+keys2_reg)*v over 64 enc rows; exp -> den atomicAdd
//       + ctx atomicAdd (fp32, zero-ahead dbuf).
//   PB (block=(row-slice rg 0..63, group bg)): MFMA gates GEMM:
//       M=16 batches x N=32 rows x K=1088, bf16 16x16x32. Weights = B-frags
//       in VGPRs (step-invariant, hi+lo bf16 split); 8 waves = 2 N-tiles x
//       4 K-slices; LDS reduce; pointwise.
// Lessons:
// R1: __threadfence/acquire => buffer_wbl2/inv per op => 65us barriers. RELAXED
//     agent-scope (sc1) atomics for all cross-block mutable data.
// R4: single-counter barrier collapses (256 spinners); fp32 Wq per-block thrashes L2.
// R5: PB staged 43MB/step of L2-bypassing sc1 reads -> ctx pre-summed, h bf16-packed.
// R6: VALU-loop gates GEMM is LDS-broadcast-bound -> MFMA w/ lane-distributed A-tile.
// R7: latency-bound: 4 groups + prestage + load-burst cut 4118->3059us.
// R8-R10: co-residency dead end: launch_bounds 2nd arg = blocks/CU here; even
//     forced 2-blk/CU can't shorten the serial chain (R10 half-work: 20us/step).
// R11: q register-cache (+32 persistent VGPR) -> spill -> 5.2GB scratch traffic.
//     FETCH_SIZE is the spill tell. Exchange mechanics themselves verified OK.

#define B 64
#define T 128
#define IN_DIM 64
#define TE 256
#define HID 512
#define ATTN 256
#define OUTD 64
#define G 256
#define BS 512

typedef __attribute__((ext_vector_type(8))) short short8;
typedef __attribute__((ext_vector_type(4))) float f32x4;

__device__ __forceinline__ float fast_exp(float x) {
  return __builtin_amdgcn_exp2f(x * 1.44269504f);
}
__device__ __forceinline__ float fast_tanh(float x) {
  float ax = fabsf(x);
  float z = __builtin_amdgcn_exp2f(ax * -2.885390082f);  // e^{-2|x|}
  float r = (1.f - z) * __builtin_amdgcn_rcpf(1.f + z);
  return copysignf(r, x);
}
__device__ __forceinline__ float fast_sig(float x) {
  float z = __builtin_amdgcn_exp2f(x * -1.44269504f);    // e^{-x}
  return __builtin_amdgcn_rcpf(1.f + z);
}
__device__ __forceinline__ float bfu(unsigned short u) {
  return __uint_as_float((unsigned)u << 16);
}
__device__ __forceinline__ float bflo(unsigned u) { return __uint_as_float(u << 16); }
__device__ __forceinline__ float bfhi(unsigned u) {
  return __uint_as_float(u & 0xffff0000u);
}
__device__ __forceinline__ unsigned f2bf(float f) {  // RNE bf16 bits
  unsigned u = __float_as_uint(f);
  return (u + 0x7fff + ((u >> 16) & 1)) >> 16;
}

// Relaxed agent-scope atomics: global_load/store ... sc1 (coherence point, no L2 flush).
__device__ __forceinline__ float ald(const float* p) {
  return __hip_atomic_load((float*)p, __ATOMIC_RELAXED, __HIP_MEMORY_SCOPE_AGENT);
}
__device__ __forceinline__ float2 ald2(const float* p) {
  double d = __hip_atomic_load((const double*)p, __ATOMIC_RELAXED,
                               __HIP_MEMORY_SCOPE_AGENT);
  union { double d; float2 f; } u; u.d = d; return u.f;
}
__device__ __forceinline__ unsigned aldu(const unsigned* p) {
  return __hip_atomic_load(p, __ATOMIC_RELAXED, __HIP_MEMORY_SCOPE_AGENT);
}
__device__ __forceinline__ void ast(float* p, float v) {
  __hip_atomic_store(p, v, __ATOMIC_RELAXED, __HIP_MEMORY_SCOPE_AGENT);
}
__device__ __forceinline__ void astu(unsigned* p, unsigned v) {
  __hip_atomic_store(p, v, __ATOMIC_RELAXED, __HIP_MEMORY_SCOPE_AGENT);
}

// Per-group flag-array barrier (64 participants). Signed >= : 0xAA poison is negative.
__device__ __forceinline__ void gridbar(int* flags, int seq, int bid, int tid) {
  asm volatile("s_waitcnt vmcnt(0)" ::: "memory");
  __syncthreads();
  if (tid == 0)
    __hip_atomic_store(&flags[bid], seq, __ATOMIC_RELAXED, __HIP_MEMORY_SCOPE_AGENT);
  if (tid < 64) {
    int* fb = flags + (bid & ~63);
    while (__hip_atomic_load(&fb[tid], __ATOMIC_RELAXED,
                             __HIP_MEMORY_SCOPE_AGENT) < seq) {
      __builtin_amdgcn_s_sleep(1);
    }
  }
  __syncthreads();
}

// fp32 -> bf16 (RNE)
__global__ void cvt_kernel(const float* __restrict__ src,
                           unsigned short* __restrict__ dst, int n) {
  for (int i = blockIdx.x * blockDim.x + threadIdx.x; i < n;
       i += gridDim.x * blockDim.x)
    dst[i] = (unsigned short)f2bf(src[i]);
}
// fp32 pairs -> packed bf16x2
__global__ void pack2_kernel(const float* __restrict__ src,
                             unsigned* __restrict__ dst, int n2) {
  for (int i = blockIdx.x * blockDim.x + threadIdx.x; i < n2;
       i += gridDim.x * blockDim.x)
    dst[i] = f2bf(src[2 * i]) | (f2bf(src[2 * i + 1]) << 16);
}

// ---- keys2[b][e][a] = bf16( sum_k enc[b][e][k] * Wk[a][k] ) ----
__global__ __launch_bounds__(256, 2) void keys_kernel(
    const float* __restrict__ enc, const float* __restrict__ Wk,
    unsigned short* __restrict__ keys2) {
  __shared__ float et[16][512];
  __shared__ float wk[32][256];
  const int tid = threadIdx.x;
  const int b = blockIdx.x >> 4;
  const int e0 = (blockIdx.x & 15) * 16;

  for (int p = 0; p < 8; ++p) {
    int i = p * 256 + tid;
    int e = i >> 7, kq = i & 127;
    float4 vv = *(const float4*)&enc[((size_t)(b * TE + e0 + e)) * HID + kq * 4];
    *(float4*)&et[e][kq * 4] = vv;
  }

  float acc[8][2];
  #pragma unroll
  for (int i = 0; i < 8; ++i) { acc[i][0] = 0.f; acc[i][1] = 0.f; }
  const int a0 = tid & 127;
  const int eh = (tid >> 7) * 8;

  for (int kc = 0; kc < 512; kc += 32) {
    __syncthreads();
    for (int p = 0; p < 8; ++p) {
      int i = p * 256 + tid;
      int a = i >> 3, j4 = (i & 7) * 4;
      float4 w4 = *(const float4*)&Wk[(size_t)a * HID + kc + j4];
      wk[j4 + 0][a] = w4.x; wk[j4 + 1][a] = w4.y;
      wk[j4 + 2][a] = w4.z; wk[j4 + 3][a] = w4.w;
    }
    __syncthreads();
    for (int k = 0; k < 32; ++k) {
      float w0 = wk[k][a0], w1 = wk[k][a0 + 128];
      #pragma unroll
      for (int i = 0; i < 8; ++i) {
        float ev = et[eh + i][kc + k];
        acc[i][0] = fmaf(ev, w0, acc[i][0]);
        acc[i][1] = fmaf(ev, w1, acc[i][1]);
      }
    }
  }
  #pragma unroll
  for (int i = 0; i < 8; ++i)
    #pragma unroll
    for (int h = 0; h < 2; ++h)
      keys2[((size_t)(b * TE + e0 + eh + i)) * ATTN + a0 + 128 * h] =
          (unsigned short)f2bf(acc[i][h]);
}

__global__ __launch_bounds__(BS, 2) void main_kernel(
    const float* __restrict__ v,
    const float* __restrict__ Wih, const float* __restrict__ Whh,
    const float* __restrict__ bih, const float* __restrict__ bhh,
    const float* __restrict__ bfc,
    const unsigned short* __restrict__ enc2, const unsigned short* __restrict__ keys2,
    const unsigned short* __restrict__ Wq2, const unsigned short* __restrict__ Wfc2,
    const unsigned* __restrict__ x2pk,
    float* hbuf, float* cbuf, float* ctxb, float* denb, unsigned* hpk,
    int* flags, int* qflag, float* qex, float* out) {
  const int bid = blockIdx.x, tid = threadIdx.x;
  const int g = bid >> 6, idx = bid & 63;           // group 0..3 / index-in-group
  const int b = g * 16 + (idx >> 2), qt = idx & 3;  // PA: batch, quarter (64 enc rows)
  const int rg = idx, bg = g;                       // PB: row-slice 0..63, group
  const int lane = tid & 63, wv = tid >> 6;

  // LDS (48.3 KB total)
  __shared__ unsigned alds[34 * 256];   // 34.8 KB A-tile [kc][m 16][16 dw, xor-swizzled]
  __shared__ float pc[2 * 4 * 16 * 17]; // 8.7 KB mfma partials [nt][kq][m][n pad17]
  __shared__ float glds[16 * 33];       // gate values [m][r pad33]
  __shared__ float hsh[HID];            // PA: staged h[b] (fp32)
  __shared__ float qsh[320];            // PA: q, swizzled idx r+(r>>2)
  __shared__ float lwsh[64];            // PA: exp weights (this quarter's rows)
  __shared__ float dsh[16];             // PB: den per batch in group
  __shared__ float blds[32];            // PB: biases

  // ---- prologue: persistent registers ----
  if (tid < 32) {
    const int gr2 = (tid >> 3) * 512 + rg * 8 + (tid & 7);
    blds[tid] = bih[gr2] + bhh[gr2];
  }
  const float4 vvf = *(const float4*)&v[lane * 4];
  float kkf[8][4];  // step-invariant keys in VGPRs (PA)
  #pragma unroll
  for (int i = 0; i < 8; ++i) {
    const unsigned short* kr =
        keys2 + ((size_t)(b * TE) + qt * 64 + wv * 8 + i) * ATTN + lane * 4;
    uint2 k4 = *(const uint2*)kr;
    kkf[i][0] = bflo(k4.x); kkf[i][1] = bfhi(k4.x);
    kkf[i][2] = bflo(k4.y); kkf[i][3] = bfhi(k4.y);
  }
  // PB mfma geometry: wave = (nt = N-tile of 16 rows, kq = K-slice)
  const int mL = lane & 15, qL = lane >> 4;
  const int nt = wv >> 2, kq = wv & 3;
  const int kstart = (kq < 2) ? kq * 9 : 18 + (kq - 2) * 8;  // 9,9,8,8 chunks of K=32
  const int nch = (kq < 2) ? 9 : 8;
  const int aoff = mL * 16 + ((qL * 4) ^ (((mL >> 1) & 3) * 4));  // A-frag dword offset
  // B-fragments (weights) in VGPRs, step-invariant: hi + lo bf16 split
  short8 bh[9], bl[9];
  {
    const int rloc = nt * 16 + mL;  // row 0..31 of this block
    const int grow2 = (rloc >> 3) * 512 + rg * 8 + (rloc & 7);
    #pragma unroll
    for (int c = 0; c < 9; ++c) {
      unsigned uh[4] = {0, 0, 0, 0}, ul[4] = {0, 0, 0, 0};
      if (c < nch) {
        const int kc = kstart + c;
        #pragma unroll
        for (int j = 0; j < 8; ++j) {
          const int k = kc * 32 + qL * 8 + j;
          const float w = (k < 576) ? Wih[(size_t)grow2 * 576 + k]
                                    : Whh[(size_t)grow2 * 512 + (k - 576)];
          const unsigned hi = f2bf(w);
          const float lo = w - __uint_as_float(hi << 16);
          uh[j >> 1] |= hi << (16 * (j & 1));
          ul[j >> 1] |= f2bf(lo) << (16 * (j & 1));
        }
      }
      uint4 th; th.x = uh[0]; th.y = uh[1]; th.z = uh[2]; th.w = uh[3];
      uint4 tl; tl.x = ul[0]; tl.y = ul[1]; tl.z = ul[2]; tl.w = ul[3];
      bh[c] = __builtin_bit_cast(short8, th);
      bl[c] = __builtin_bit_cast(short8, tl);
    }
  }

  // Staging thread geometry (shared by PA-prestage and PB ctx staging)
  const int sm = tid >> 5, ss = tid & 31;
  const int bgl = bg * 16 + sm;
  const int dcol = (ss & 15) ^ (((sm >> 1) & 3) * 4);
  // q-slice geometry: 8 threads per q-row, rows qt*64..qt*64+63
  const int qrow = qt * 64 + (tid >> 3);
  const int qg = tid & 7;

  int seq = 0;

  for (int t = 0; t < T; ++t) {
    // ================= PA: attention in-block =================
    {
      const float* hprev = hbuf + (size_t)(t & 1) * B * HID;
      hsh[tid] = ald(hprev + (size_t)b * HID + tid);
      // ---- prestage x + h A-tile rows (visible since previous barrier) ----
      {
        unsigned pkx = x2pk[((size_t)bgl * T + t) * 32 + ss];
        const unsigned* hpkc = hpk + (size_t)(t & 1) * B * 256 + (size_t)bgl * 256;
        unsigned ph[8];
        #pragma unroll
        for (int p = 0; p < 8; ++p) ph[p] = aldu(hpkc + ss + 32 * p);
        alds[(ss >> 4) * 256 + sm * 16 + dcol] = pkx;     // kc rows 0..1
        #pragma unroll
        for (int p = 0; p < 8; ++p) {                     // kc rows 18..33
          const int i = ss + 32 * (p + 9);
          alds[(i >> 4) * 256 + sm * 16 + dcol] = ph[p];
        }
      }
      __syncthreads();  // hsh ready
      {  // q-slice: 64 MACs from L2-weights x LDS-h, 8-lane reduce -> qex store
        const uint4* wq4 = (const uint4*)(Wq2 + (size_t)qrow * HID + qg * 64);
        const float* hb = &hsh[qg * 64];
        float qa0 = 0.f, qa1 = 0.f;
        #pragma unroll
        for (int j0 = 0; j0 < 8; ++j0) {
          const int j = (j0 + qg) & 7;  // bank-stagger the hsh reads across qg
          uint4 w8 = wq4[j];
          const float* hp = hb + j * 8;
          qa0 = fmaf(bflo(w8.x), hp[0], qa0); qa0 = fmaf(bfhi(w8.x), hp[1], qa0);
          qa0 = fmaf(bflo(w8.y), hp[2], qa0); qa0 = fmaf(bfhi(w8.y), hp[3], qa0);
          qa1 = fmaf(bflo(w8.z), hp[4], qa1); qa1 = fmaf(bfhi(w8.z), hp[5], qa1);
          qa1 = fmaf(bflo(w8.w), hp[6], qa1); qa1 = fmaf(bfhi(w8.w), hp[7], qa1);
        }
        float qa = qa0 + qa1;
        qa += __shfl_xor(qa, 1, 64); qa += __shfl_xor(qa, 2, 64);
        qa += __shfl_xor(qa, 4, 64);
        if (qg == 0) ast(qex + (size_t)b * 256 + qrow, qa);
      }
      // drain q stores, then publish flag
      asm volatile("s_waitcnt vmcnt(0)" ::: "memory");
      __syncthreads();
      if (tid == 0)
        __hip_atomic_store(&qflag[b * 4 + qt], t + 1, __ATOMIC_RELAXED,
                           __HIP_MEMORY_SCOPE_AGENT);
      // ---- exchange-latency fill: out(t-1) + zero-ahead ----
      if (t >= 1 && tid < 128) {  // out(t-1): 16 outputs per quarter
        const int o = qt * 16 + (tid >> 3), c = tid & 7;
        const unsigned short* wr = Wfc2 + (size_t)o * HID;
        float oa = 0.f;
        #pragma unroll
        for (int j = 0; j < 8; ++j) {
          const int jj = c * 64 + ((j + c) & 7) * 8;
          uint4 w8 = *(const uint4*)(wr + jj);
          const float* hp = &hsh[jj];
          oa = fmaf(bflo(w8.x), hp[0], oa); oa = fmaf(bfhi(w8.x), hp[1], oa);
          oa = fmaf(bflo(w8.y), hp[2], oa); oa = fmaf(bfhi(w8.y), hp[3], oa);
          oa = fmaf(bflo(w8.z), hp[4], oa); oa = fmaf(bfhi(w8.z), hp[5], oa);
          oa = fmaf(bflo(w8.w), hp[6], oa); oa = fmaf(bfhi(w8.w), hp[7], oa);
        }
        oa += __shfl_xor(oa, 1, 64); oa += __shfl_xor(oa, 2, 64);
        oa += __shfl_xor(oa, 4, 64);
        if (c == 0) out[((size_t)b * T + (t - 1)) * OUTD + o] = oa + bfc[o];
      }
      // zero next step's accumulators (barrier-separated from their reuse)
      if (tid < 128)
        ast(ctxb + (size_t)((t + 1) & 1) * B * HID + b * HID + qt * 128 + tid, 0.f);
      if (qt == 0 && tid == 0) ast(denb + ((t + 1) & 1) * B + b, 0.f);
      // ---- poll 3 sibling q-slices, assemble full q ----
      if (tid < 4 && tid != qt) {
        while (__hip_atomic_load(&qflag[b * 4 + tid], __ATOMIC_RELAXED,
                                 __HIP_MEMORY_SCOPE_AGENT) < t + 1) {
          __builtin_amdgcn_s_sleep(1);
        }
      }
      __syncthreads();  // siblings' flags seen (their qex drained before flag)
      if (tid < 256) qsh[tid + (tid >> 2)] = ald(qex + (size_t)b * 256 + tid);
      __syncthreads();
      {  // energies: 8 rows per wave
        float q4[4];
        #pragma unroll
        for (int j = 0; j < 4; ++j) q4[j] = qsh[5 * lane + j];
        #pragma unroll
        for (int i = 0; i < 8; ++i) {
          float p = fast_tanh(q4[0] + kkf[i][0]) * vvf.x;
          p = fmaf(fast_tanh(q4[1] + kkf[i][1]), vvf.y, p);
          p = fmaf(fast_tanh(q4[2] + kkf[i][2]), vvf.z, p);
          p = fmaf(fast_tanh(q4[3] + kkf[i][3]), vvf.w, p);
          #pragma unroll
          for (int m = 1; m < 64; m <<= 1) p += __shfl_xor(p, m, 64);
          if (lane == 0) lwsh[wv * 8 + i] = fast_exp(p);
        }
      }
      __syncthreads();
      if (tid < 64) {  // den partial
        float p = lwsh[tid];
        #pragma unroll
        for (int m = 1; m < 64; m <<= 1) p += __shfl_xor(p, m, 64);
        if (tid == 0) atomicAdd(denb + (t & 1) * B + b, p);
      }
      {  // ctx partial over 64 enc2 rows -> atomicAdd
        const unsigned short* erow = enc2 + ((size_t)(b * TE) + qt * 64) * HID + tid;
        float a0 = 0.f, a1 = 0.f, a2 = 0.f, a3 = 0.f;
        #pragma unroll
        for (int e = 0; e < 64; e += 4) {
          a0 = fmaf(lwsh[e],     bfu(erow[(size_t)e * HID]),       a0);
          a1 = fmaf(lwsh[e + 1], bfu(erow[(size_t)(e + 1) * HID]), a1);
          a2 = fmaf(lwsh[e + 2], bfu(erow[(size_t)(e + 2) * HID]), a2);
          a3 = fmaf(lwsh[e + 3], bfu(erow[(size_t)(e + 3) * HID]), a3);
        }
        atomicAdd(ctxb + (size_t)(t & 1) * B * HID + b * HID + tid,
                  (a0 + a1) + (a2 + a3));
      }
    }
    ++seq; gridbar(flags, seq, bid, tid);

    // ================= PB: MFMA gates + LSTM update =================
    {
      float* hnext = hbuf + (size_t)((t + 1) & 1) * B * HID;
      const float* ctxcur = ctxb + (size_t)(t & 1) * B * HID;
      // ---- one load burst: den + 16 ctx floats per thread (no serialization) ----
      if (tid < 16) dsh[tid] = ald(denb + (t & 1) * B + bg * 16 + tid);
      float2 cv[8];
      #pragma unroll
      for (int p = 0; p < 8; ++p)
        cv[p] = ald2(ctxcur + (size_t)bgl * HID + (2 * (ss + 32 * (p + 1)) - 64));
      __syncthreads();  // dsh ready
      {  // ctx: *1/den -> bf16 pack -> A-tile kc rows 2..17
        const float li = __builtin_amdgcn_rcpf(dsh[sm]);
        #pragma unroll
        for (int p = 0; p < 8; ++p) {
          const int i = ss + 32 * (p + 1);
          unsigned pk = f2bf(cv[p].x * li) | (f2bf(cv[p].y * li) << 16);
          alds[(i >> 4) * 256 + sm * 16 + dcol] = pk;
        }
      }
      __syncthreads();
      // ---- MFMA: 8-9 chunks, hi+lo weight split ----
      {
        f32x4 ach = {0.f, 0.f, 0.f, 0.f}, acl = {0.f, 0.f, 0.f, 0.f};
        #pragma unroll
        for (int c = 0; c < 9; ++c) {
          if (c < nch) {
            const uint4 av = *(const uint4*)&alds[(kstart + c) * 256 + aoff];
            const short8 a8 = __builtin_bit_cast(short8, av);
            ach = __builtin_amdgcn_mfma_f32_16x16x32_bf16(a8, bh[c], ach, 0, 0, 0);
            acl = __builtin_amdgcn_mfma_f32_16x16x32_bf16(a8, bl[c], acl, 0, 0, 0);
          }
        }
        #pragma unroll
        for (int rr = 0; rr < 4; ++rr)
          pc[((nt * 4 + kq) * 16 + qL * 4 + rr) * 17 + mL] = ach[rr] + acl[rr];
      }
      __syncthreads();
      {  // reduce 4 K-slices + bias -> glds[m][r]
        const int r2 = tid >> 4, mb = tid & 15;
        const int pbase = ((r2 >> 4) * 64 + mb) * 17 + (r2 & 15);
        float s = blds[r2] + ((pc[pbase] + pc[pbase + 272]) +
                              (pc[pbase + 544] + pc[pbase + 816]));
        glds[mb * 33 + r2] = s;
      }
      __syncthreads();
      if (tid < 128) {  // pointwise LSTM: 16 batches x 8 rows
        const int bbl = tid >> 3, hl = tid & 7;
        const int bb2 = bg * 16 + bbl, hu = rg * 8 + hl;
        const float gi = glds[bbl * 33 + hl],      gf = glds[bbl * 33 + 8 + hl];
        const float gg = glds[bbl * 33 + 16 + hl], go = glds[bbl * 33 + 24 + hl];
        const float cold = cbuf[bb2 * HID + hu];  // block-private: plain cached ok
        const float cn = fast_sig(gf) * cold + fast_sig(gi) * fast_tanh(gg);
        const float hn = fast_sig(go) * fast_tanh(cn);
        cbuf[bb2 * HID + hu] = cn;
        ast(&hnext[bb2 * HID + hu], hn);            // fp32 for PA
        const float ho = __shfl_xor(hn, 1, 64);     // bf16 pair for next PB
        if ((hl & 1) == 0)
          astu(hpk + (size_t)((t + 1) & 1) * B * 256 + bb2 * 256 + rg * 4 + (hl >> 1),
               f2bf(hn) | (f2bf(ho) << 16));
      }
    }
    ++seq; gridbar(flags, seq, bid, tid);
  }

  // ---------------- epilogue: out(127) from h_128 (hbuf slot 0) ----------------
  {
    hsh[tid] = ald(hbuf + (size_t)b * HID + tid);
    __syncthreads();
    if (tid < 128) {
      const int o = qt * 16 + (tid >> 3), c = tid & 7;
      const unsigned short* wr = Wfc2 + (size_t)o * HID;
      float oa = 0.f;
      #pragma unroll
      for (int j = 0; j < 8; ++j) {
        const int jj = c * 64 + ((j + c) & 7) * 8;
        uint4 w8 = *(const uint4*)(wr + jj);
        const float* hp = &hsh[jj];
        oa = fmaf(bflo(w8.x), hp[0], oa); oa = fmaf(bfhi(w8.x), hp[1], oa);
        oa = fmaf(bflo(w8.y), hp[2], oa); oa = fmaf(bfhi(w8.y), hp[3], oa);
        oa = fmaf(bflo(w8.z), hp[4], oa); oa = fmaf(bfhi(w8.z), hp[5], oa);
        oa = fmaf(bflo(w8.w), hp[6], oa); oa = fmaf(bfhi(w8.w), hp[7], oa);
      }
      oa += __shfl_xor(oa, 1, 64); oa += __shfl_xor(oa, 2, 64);
      oa += __shfl_xor(oa, 4, 64);
      if (c == 0) out[((size_t)b * T + 127) * OUTD + o] = oa + bfc[o];
    }
  }
}

extern "C" void kernel_launch(void* const* d_in, const int* in_sizes, int n_in,
                              void* d_out, int out_size, void* d_ws, size_t ws_size,
                              hipStream_t stream) {
  const float* x   = (const float*)d_in[0];
  const float* enc = (const float*)d_in[1];
  const float* Wq  = (const float*)d_in[2];
  const float* Wk  = (const float*)d_in[3];
  const float* v   = (const float*)d_in[4];
  const float* Wih = (const float*)d_in[5];
  const float* Whh = (const float*)d_in[6];
  const float* bih = (const float*)d_in[7];
  const float* bhh = (const float*)d_in[8];
  const float* Wfc = (const float*)d_in[9];
  const float* bfc = (const float*)d_in[10];

  // ws layout (~28.5 MB)
  unsigned short* enc2  = (unsigned short*)d_ws;          // B*TE*HID
  unsigned short* keys2 = enc2 + (size_t)B * TE * HID;    // B*TE*ATTN
  unsigned short* Wq2   = keys2 + (size_t)B * TE * ATTN;  // ATTN*HID
  unsigned short* Wfc2  = Wq2 + ATTN * HID;               // OUTD*HID
  float* hbuf = (float*)(Wfc2 + OUTD * HID);  // 2*B*HID fp32
  float* cbuf = hbuf + 2 * B * HID;           // B*HID
  float* ctxb = cbuf + B * HID;               // 2*B*HID (dbuf accumulators)
  float* denb = ctxb + 2 * B * HID;           // 2*B
  unsigned* hpk = (unsigned*)(denb + 2 * B);  // 2*B*256 packed bf16 h (dbuf)
  int* flags = (int*)(hpk + 2 * B * 256);     // 256
  int* qflag = flags + 256;                   // 256 (B*4)
  unsigned* x2pk = (unsigned*)(qflag + 256);  // B*T*32 packed bf16 x
  float* qex = (float*)(x2pk + (size_t)B * T * 32);  // B*256 fp32 q exchange

  // zero hbuf|cbuf|ctxb|denb|hpk|flags|qflag (contiguous) every call
  const size_t zero_units = 2 * B * HID + B * HID + 2 * B * HID + 2 * B +
                            2 * B * 256 + 256 + 256;
  hipMemsetAsync(hbuf, 0, zero_units * 4, stream);

  cvt_kernel<<<dim3(512), dim3(256), 0, stream>>>(enc, enc2, B * TE * HID);
  cvt_kernel<<<dim3(64), dim3(256), 0, stream>>>(Wq, Wq2, ATTN * HID);
  cvt_kernel<<<dim3(32), dim3(256), 0, stream>>>(Wfc, Wfc2, OUTD * HID);
  pack2_kernel<<<dim3(128), dim3(256), 0, stream>>>(x, x2pk, B * T * 32);
  keys_kernel<<<dim3(1024), dim3(256), 0, stream>>>(enc, Wk, keys2);
  main_kernel<<<dim3(G), dim3(BS), 0, stream>>>(
      v, Wih, Whh, bih, bhh, bfc, enc2, keys2, Wq2, Wfc2, x2pk,
      hbuf, cbuf, ctxb, denb, hpk, flags, qflag, qex, (float*)d_out);
}

// Round 7
// 3214.644 us; speedup vs baseline: 2.4999x; 2.4999x over previous
//
#include <hip/hip_runtime.h>

// LSTM decoder w/ Bahdanau attention, MI355X.
// Persistent grid-synchronized kernel R13 = R7 champion (verified 3322us)
// with widened register margin: q-loop unroll 8->4 (halves transient uint4
// loads in flight at the peak-pressure program point). NO other changes.
// 256 blocks x 512 threads (1 block/CU), 4 INDEPENDENT GROUPS of 64 blocks
// (16 batches each) with per-group flag barriers.
// TWO per-group barriers per step:
//   PA (block=(batch b, quarter qt)): stage h[b](fp32)->LDS; prestage x/h
//       A-tile rows; q=h@Wq2^T (full 256, redundant x4); out(t-1) 16 rows;
//       energies tanh(q+keys2_reg)*v; unnormalized exp -> den atomicAdd +
//       ctx atomicAdd (fp32, zero-ahead dbuf).
//   PB (block=(row-slice rg, group bg)): MFMA gates GEMM:
//       M=16 batches x N=32 rows x K=1088, bf16 16x16x32. Weights = B-frags
//       in VGPRs (step-invariant, hi+lo bf16 split); 8 waves = 2 N-tiles x
//       4 K-slices; LDS reduce; pointwise.
// Lessons:
// R1: __threadfence/acquire => buffer_wbl2/inv per op => 65us barriers. RELAXED
//     agent-scope (sc1) atomics for all cross-block mutable data.
// R4: single-counter barrier collapses (256 spinners); fp32 Wq per-block thrashes L2.
// R5: PB staged 43MB/step of L2-bypassing sc1 reads -> ctx pre-summed, h bf16-packed.
// R6: VALU-loop gates GEMM is LDS-broadcast-bound -> MFMA w/ lane-distributed A-tile.
// R7: latency-bound (12.6% VALUBusy): 4 groups + prestage + load-burst 4118->3059us.
// R8-R10: co-residency dead end: launch_bounds 2nd arg = blocks/CU on this
//     toolchain; forced 2-blk/CU can't shorten the serial chain anyway.
// R11/R12: REGISTER CLIFF. This kernel is at exactly 128 VGPR; ANY addition
//     (R11: +32 persistent wqr; R12: +transient addressing in q-slice path)
//     spills the loop-carried bh/bl weight frags -> ~5GB/dispatch scratch
//     reload (FETCH_SIZE is the tell; VGPR_Count stays 128), VALU 4%, 2.3x
//     regression + near-hang outliers. Cross-XCD qflag/qex fine-grained
//     exchange also implicated in 45-48ms outlier dispatches. Verdict:
//     never add state to this kernel without first widening reg margin.

#define B 64
#define T 128
#define IN_DIM 64
#define TE 256
#define HID 512
#define ATTN 256
#define OUTD 64
#define G 256
#define BS 512

typedef __attribute__((ext_vector_type(8))) short short8;
typedef __attribute__((ext_vector_type(4))) float f32x4;

__device__ __forceinline__ float fast_exp(float x) {
  return __builtin_amdgcn_exp2f(x * 1.44269504f);
}
__device__ __forceinline__ float fast_tanh(float x) {
  float ax = fabsf(x);
  float z = __builtin_amdgcn_exp2f(ax * -2.885390082f);  // e^{-2|x|}
  float r = (1.f - z) * __builtin_amdgcn_rcpf(1.f + z);
  return copysignf(r, x);
}
__device__ __forceinline__ float fast_sig(float x) {
  float z = __builtin_amdgcn_exp2f(x * -1.44269504f);    // e^{-x}
  return __builtin_amdgcn_rcpf(1.f + z);
}
__device__ __forceinline__ float bfu(unsigned short u) {
  return __uint_as_float((unsigned)u << 16);
}
__device__ __forceinline__ float bflo(unsigned u) { return __uint_as_float(u << 16); }
__device__ __forceinline__ float bfhi(unsigned u) {
  return __uint_as_float(u & 0xffff0000u);
}
__device__ __forceinline__ unsigned f2bf(float f) {  // RNE bf16 bits
  unsigned u = __float_as_uint(f);
  return (u + 0x7fff + ((u >> 16) & 1)) >> 16;
}

// Relaxed agent-scope atomics: global_load/store ... sc1 (coherence point, no L2 flush).
__device__ __forceinline__ float ald(const float* p) {
  return __hip_atomic_load((float*)p, __ATOMIC_RELAXED, __HIP_MEMORY_SCOPE_AGENT);
}
__device__ __forceinline__ float2 ald2(const float* p) {
  double d = __hip_atomic_load((const double*)p, __ATOMIC_RELAXED,
                               __HIP_MEMORY_SCOPE_AGENT);
  union { double d; float2 f; } u; u.d = d; return u.f;
}
__device__ __forceinline__ unsigned aldu(const unsigned* p) {
  return __hip_atomic_load(p, __ATOMIC_RELAXED, __HIP_MEMORY_SCOPE_AGENT);
}
__device__ __forceinline__ void ast(float* p, float v) {
  __hip_atomic_store(p, v, __ATOMIC_RELAXED, __HIP_MEMORY_SCOPE_AGENT);
}
__device__ __forceinline__ void astu(unsigned* p, unsigned v) {
  __hip_atomic_store(p, v, __ATOMIC_RELAXED, __HIP_MEMORY_SCOPE_AGENT);
}

// Per-group flag-array barrier (64 participants). Signed >= : 0xAA poison is negative.
__device__ __forceinline__ void gridbar(int* flags, int seq, int bid, int tid) {
  asm volatile("s_waitcnt vmcnt(0)" ::: "memory");
  __syncthreads();
  if (tid == 0)
    __hip_atomic_store(&flags[bid], seq, __ATOMIC_RELAXED, __HIP_MEMORY_SCOPE_AGENT);
  if (tid < 64) {
    int* fb = flags + (bid & ~63);
    while (__hip_atomic_load(&fb[tid], __ATOMIC_RELAXED,
                             __HIP_MEMORY_SCOPE_AGENT) < seq) {
      __builtin_amdgcn_s_sleep(1);
    }
  }
  __syncthreads();
}

// fp32 -> bf16 (RNE)
__global__ void cvt_kernel(const float* __restrict__ src,
                           unsigned short* __restrict__ dst, int n) {
  for (int i = blockIdx.x * blockDim.x + threadIdx.x; i < n;
       i += gridDim.x * blockDim.x)
    dst[i] = (unsigned short)f2bf(src[i]);
}
// fp32 pairs -> packed bf16x2
__global__ void pack2_kernel(const float* __restrict__ src,
                             unsigned* __restrict__ dst, int n2) {
  for (int i = blockIdx.x * blockDim.x + threadIdx.x; i < n2;
       i += gridDim.x * blockDim.x)
    dst[i] = f2bf(src[2 * i]) | (f2bf(src[2 * i + 1]) << 16);
}

// ---- keys2[b][e][a] = bf16( sum_k enc[b][e][k] * Wk[a][k] ) ----
__global__ __launch_bounds__(256, 2) void keys_kernel(
    const float* __restrict__ enc, const float* __restrict__ Wk,
    unsigned short* __restrict__ keys2) {
  __shared__ float et[16][512];
  __shared__ float wk[32][256];
  const int tid = threadIdx.x;
  const int b = blockIdx.x >> 4;
  const int e0 = (blockIdx.x & 15) * 16;

  for (int p = 0; p < 8; ++p) {
    int i = p * 256 + tid;
    int e = i >> 7, kq = i & 127;
    float4 vv = *(const float4*)&enc[((size_t)(b * TE + e0 + e)) * HID + kq * 4];
    *(float4*)&et[e][kq * 4] = vv;
  }

  float acc[8][2];
  #pragma unroll
  for (int i = 0; i < 8; ++i) { acc[i][0] = 0.f; acc[i][1] = 0.f; }
  const int a0 = tid & 127;
  const int eh = (tid >> 7) * 8;

  for (int kc = 0; kc < 512; kc += 32) {
    __syncthreads();
    for (int p = 0; p < 8; ++p) {
      int i = p * 256 + tid;
      int a = i >> 3, j4 = (i & 7) * 4;
      float4 w4 = *(const float4*)&Wk[(size_t)a * HID + kc + j4];
      wk[j4 + 0][a] = w4.x; wk[j4 + 1][a] = w4.y;
      wk[j4 + 2][a] = w4.z; wk[j4 + 3][a] = w4.w;
    }
    __syncthreads();
    for (int k = 0; k < 32; ++k) {
      float w0 = wk[k][a0], w1 = wk[k][a0 + 128];
      #pragma unroll
      for (int i = 0; i < 8; ++i) {
        float ev = et[eh + i][kc + k];
        acc[i][0] = fmaf(ev, w0, acc[i][0]);
        acc[i][1] = fmaf(ev, w1, acc[i][1]);
      }
    }
  }
  #pragma unroll
  for (int i = 0; i < 8; ++i)
    #pragma unroll
    for (int h = 0; h < 2; ++h)
      keys2[((size_t)(b * TE + e0 + eh + i)) * ATTN + a0 + 128 * h] =
          (unsigned short)f2bf(acc[i][h]);
}

__global__ __launch_bounds__(BS, 2) void main_kernel(
    const float* __restrict__ v,
    const float* __restrict__ Wih, const float* __restrict__ Whh,
    const float* __restrict__ bih, const float* __restrict__ bhh,
    const float* __restrict__ bfc,
    const unsigned short* __restrict__ enc2, const unsigned short* __restrict__ keys2,
    const unsigned short* __restrict__ Wq2, const unsigned short* __restrict__ Wfc2,
    const unsigned* __restrict__ x2pk,
    float* hbuf, float* cbuf, float* ctxb, float* denb, unsigned* hpk,
    int* flags, float* out) {
  const int bid = blockIdx.x, tid = threadIdx.x;
  const int g = bid >> 6, idx = bid & 63;      // group / index-in-group
  const int b = g * 16 + (idx >> 2), qt = idx & 3;  // PA role
  const int rg = idx, bg = g;                  // PB role
  const int lane = tid & 63, wv = tid >> 6;

  // LDS (48.3 KB total)
  __shared__ unsigned alds[34 * 256];   // 34.8 KB A-tile [kc][m 16][16 dw, xor-swizzled]
  __shared__ float pc[2 * 4 * 16 * 17]; // 8.7 KB mfma partials [nt][kq][m][n pad17]
  __shared__ float glds[16 * 33];       // gate values [m][r pad33]
  __shared__ float hsh[HID];            // PA: staged h[b] (fp32)
  __shared__ float qsh[320];            // PA: q, swizzled idx r+(r>>2)
  __shared__ float lwsh[64];            // PA: exp weights (this quarter's rows)
  __shared__ float dsh[16];             // PB: den per batch in group
  __shared__ float blds[32];            // PB: biases

  // ---- prologue: persistent registers ----
  if (tid < 32) {
    const int gr2 = (tid >> 3) * 512 + rg * 8 + (tid & 7);
    blds[tid] = bih[gr2] + bhh[gr2];
  }
  const float4 vvf = *(const float4*)&v[lane * 4];
  float kkf[8][4];  // step-invariant keys in VGPRs (PA)
  #pragma unroll
  for (int i = 0; i < 8; ++i) {
    const unsigned short* kr =
        keys2 + ((size_t)(b * TE) + qt * 64 + wv * 8 + i) * ATTN + lane * 4;
    uint2 k4 = *(const uint2*)kr;
    kkf[i][0] = bflo(k4.x); kkf[i][1] = bfhi(k4.x);
    kkf[i][2] = bflo(k4.y); kkf[i][3] = bfhi(k4.y);
  }
  // PB mfma geometry: wave = (nt = N-tile of 16 rows, kq = K-slice)
  const int mL = lane & 15, qL = lane >> 4;
  const int nt = wv >> 2, kq = wv & 3;
  const int kstart = (kq < 2) ? kq * 9 : 18 + (kq - 2) * 8;  // 9,9,8,8 chunks of K=32
  const int nch = (kq < 2) ? 9 : 8;
  const int aoff = mL * 16 + ((qL * 4) ^ (((mL >> 1) & 3) * 4));  // A-frag dword offset
  // B-fragments (weights) in VGPRs, step-invariant: hi + lo bf16 split
  short8 bh[9], bl[9];
  {
    const int rloc = nt * 16 + mL;  // row 0..31 of this block
    const int grow2 = (rloc >> 3) * 512 + rg * 8 + (rloc & 7);
    #pragma unroll
    for (int c = 0; c < 9; ++c) {
      unsigned uh[4] = {0, 0, 0, 0}, ul[4] = {0, 0, 0, 0};
      if (c < nch) {
        const int kc = kstart + c;
        #pragma unroll
        for (int j = 0; j < 8; ++j) {
          const int k = kc * 32 + qL * 8 + j;
          const float w = (k < 576) ? Wih[(size_t)grow2 * 576 + k]
                                    : Whh[(size_t)grow2 * 512 + (k - 576)];
          const unsigned hi = f2bf(w);
          const float lo = w - __uint_as_float(hi << 16);
          uh[j >> 1] |= hi << (16 * (j & 1));
          ul[j >> 1] |= f2bf(lo) << (16 * (j & 1));
        }
      }
      uint4 th; th.x = uh[0]; th.y = uh[1]; th.z = uh[2]; th.w = uh[3];
      uint4 tl; tl.x = ul[0]; tl.y = ul[1]; tl.z = ul[2]; tl.w = ul[3];
      bh[c] = __builtin_bit_cast(short8, th);
      bl[c] = __builtin_bit_cast(short8, tl);
    }
  }

  // Staging thread geometry (shared by PA-prestage and PB ctx staging)
  const int sm = tid >> 5, ss = tid & 31;
  const int bgl = bg * 16 + sm;
  const int dcol = (ss & 15) ^ (((sm >> 1) & 3) * 4);

  int seq = 0;

  for (int t = 0; t < T; ++t) {
    // ================= PA: attention in-block =================
    {
      const float* hprev = hbuf + (size_t)(t & 1) * B * HID;
      hsh[tid] = ald(hprev + (size_t)b * HID + tid);
      // ---- prestage x + h A-tile rows (visible since previous barrier) ----
      {
        unsigned pkx = x2pk[((size_t)bgl * T + t) * 32 + ss];
        const unsigned* hpkc = hpk + (size_t)(t & 1) * B * 256 + (size_t)bgl * 256;
        unsigned ph[8];
        #pragma unroll
        for (int p = 0; p < 8; ++p) ph[p] = aldu(hpkc + ss + 32 * p);
        alds[(ss >> 4) * 256 + sm * 16 + dcol] = pkx;     // kc rows 0..1
        #pragma unroll
        for (int p = 0; p < 8; ++p) {                     // kc rows 18..33
          const int i = ss + 32 * (p + 9);
          alds[(i >> 4) * 256 + sm * 16 + dcol] = ph[p];
        }
      }
      __syncthreads();
      if (t >= 1 && tid < 128) {  // out(t-1): 16 outputs per quarter, rotated k-chunks
        const int o = qt * 16 + (tid >> 3), c = tid & 7;
        const unsigned short* wr = Wfc2 + (size_t)o * HID;
        float oa = 0.f;
        #pragma unroll
        for (int j = 0; j < 8; ++j) {
          const int jj = c * 64 + ((j + c) & 7) * 8;
          uint4 w8 = *(const uint4*)(wr + jj);
          const float* hp = &hsh[jj];
          oa = fmaf(bflo(w8.x), hp[0], oa); oa = fmaf(bfhi(w8.x), hp[1], oa);
          oa = fmaf(bflo(w8.y), hp[2], oa); oa = fmaf(bfhi(w8.y), hp[3], oa);
          oa = fmaf(bflo(w8.z), hp[4], oa); oa = fmaf(bfhi(w8.z), hp[5], oa);
          oa = fmaf(bflo(w8.w), hp[6], oa); oa = fmaf(bfhi(w8.w), hp[7], oa);
        }
        oa += __shfl_xor(oa, 1, 64); oa += __shfl_xor(oa, 2, 64);
        oa += __shfl_xor(oa, 4, 64);
        if (c == 0) out[((size_t)b * T + (t - 1)) * OUTD + o] = oa + bfc[o];
      }
      {  // q[256] = h @ Wq2^T: 2 threads/row, dual accumulators.
         // unroll 4 (not 8): halves in-flight uint4 temporaries -> register
         // headroom below the 128-VGPR cliff (R11/R12 lesson).
        const int r = tid >> 1, c2 = tid & 1;
        const unsigned short* wr = Wq2 + (size_t)r * HID + c2 * 256;
        const float* hb = &hsh[c2 * 256];
        float qa0 = 0.f, qa1 = 0.f;
        #pragma unroll 4
        for (int j = 0; j < 32; ++j) {
          uint4 w8 = ((const uint4*)wr)[j];
          const float* hp = hb + j * 8;
          qa0 = fmaf(bflo(w8.x), hp[0], qa0); qa0 = fmaf(bfhi(w8.x), hp[1], qa0);
          qa0 = fmaf(bflo(w8.y), hp[2], qa0); qa0 = fmaf(bfhi(w8.y), hp[3], qa0);
          qa1 = fmaf(bflo(w8.z), hp[4], qa1); qa1 = fmaf(bfhi(w8.z), hp[5], qa1);
          qa1 = fmaf(bflo(w8.w), hp[6], qa1); qa1 = fmaf(bfhi(w8.w), hp[7], qa1);
        }
        float qa = qa0 + qa1;
        qa += __shfl_xor(qa, 1, 64);
        if (c2 == 0) qsh[r + (r >> 2)] = qa;
      }
      __syncthreads();
      {  // energies
        float q4[4];
        #pragma unroll
        for (int j = 0; j < 4; ++j) q4[j] = qsh[5 * lane + j];
        #pragma unroll
        for (int i = 0; i < 8; ++i) {
          float p = fast_tanh(q4[0] + kkf[i][0]) * vvf.x;
          p = fmaf(fast_tanh(q4[1] + kkf[i][1]), vvf.y, p);
          p = fmaf(fast_tanh(q4[2] + kkf[i][2]), vvf.z, p);
          p = fmaf(fast_tanh(q4[3] + kkf[i][3]), vvf.w, p);
          #pragma unroll
          for (int m = 1; m < 64; m <<= 1) p += __shfl_xor(p, m, 64);
          if (lane == 0) lwsh[wv * 8 + i] = fast_exp(p);
        }
      }
      __syncthreads();
      if (tid < 64) {  // den partial
        float p = lwsh[tid];
        #pragma unroll
        for (int m = 1; m < 64; m <<= 1) p += __shfl_xor(p, m, 64);
        if (tid == 0) atomicAdd(denb + (t & 1) * B + b, p);
      }
      // zero next step's accumulators (barrier-separated)
      if (tid < 128)
        ast(ctxb + (size_t)((t + 1) & 1) * B * HID + b * HID + qt * 128 + tid, 0.f);
      if (qt == 0 && tid == 0) ast(denb + ((t + 1) & 1) * B + b, 0.f);
      {  // ctx partial over 64 enc2 rows -> atomicAdd
        const unsigned short* erow = enc2 + ((size_t)(b * TE) + qt * 64) * HID + tid;
        float a0 = 0.f, a1 = 0.f, a2 = 0.f, a3 = 0.f;
        #pragma unroll
        for (int e = 0; e < 64; e += 4) {
          a0 = fmaf(lwsh[e],     bfu(erow[(size_t)e * HID]),       a0);
          a1 = fmaf(lwsh[e + 1], bfu(erow[(size_t)(e + 1) * HID]), a1);
          a2 = fmaf(lwsh[e + 2], bfu(erow[(size_t)(e + 2) * HID]), a2);
          a3 = fmaf(lwsh[e + 3], bfu(erow[(size_t)(e + 3) * HID]), a3);
        }
        atomicAdd(ctxb + (size_t)(t & 1) * B * HID + b * HID + tid,
                  (a0 + a1) + (a2 + a3));
      }
    }
    ++seq; gridbar(flags, seq, bid, tid);

    // ================= PB: MFMA gates + LSTM update =================
    {
      float* hnext = hbuf + (size_t)((t + 1) & 1) * B * HID;
      const float* ctxcur = ctxb + (size_t)(t & 1) * B * HID;
      // ---- one load burst: den + 16 ctx floats per thread (no serialization) ----
      if (tid < 16) dsh[tid] = ald(denb + (t & 1) * B + bg * 16 + tid);
      float2 cv[8];
      #pragma unroll
      for (int p = 0; p < 8; ++p)
        cv[p] = ald2(ctxcur + (size_t)bgl * HID + (2 * (ss + 32 * (p + 1)) - 64));
      __syncthreads();  // dsh ready
      {  // ctx: *1/den -> bf16 pack -> A-tile kc rows 2..17
        const float li = __builtin_amdgcn_rcpf(dsh[sm]);
        #pragma unroll
        for (int p = 0; p < 8; ++p) {
          const int i = ss + 32 * (p + 1);
          unsigned pk = f2bf(cv[p].x * li) | (f2bf(cv[p].y * li) << 16);
          alds[(i >> 4) * 256 + sm * 16 + dcol] = pk;
        }
      }
      __syncthreads();
      // ---- MFMA: 8-9 chunks, hi+lo weight split ----
      {
        f32x4 ach = {0.f, 0.f, 0.f, 0.f}, acl = {0.f, 0.f, 0.f, 0.f};
        #pragma unroll
        for (int c = 0; c < 9; ++c) {
          if (c < nch) {
            const uint4 av = *(const uint4*)&alds[(kstart + c) * 256 + aoff];
            const short8 a8 = __builtin_bit_cast(short8, av);
            ach = __builtin_amdgcn_mfma_f32_16x16x32_bf16(a8, bh[c], ach, 0, 0, 0);
            acl = __builtin_amdgcn_mfma_f32_16x16x32_bf16(a8, bl[c], acl, 0, 0, 0);
          }
        }
        #pragma unroll
        for (int rr = 0; rr < 4; ++rr)
          pc[((nt * 4 + kq) * 16 + qL * 4 + rr) * 17 + mL] = ach[rr] + acl[rr];
      }
      __syncthreads();
      {  // reduce 4 K-slices + bias -> glds[m][r]
        const int r2 = tid >> 4, mb = tid & 15;
        const int pbase = ((r2 >> 4) * 64 + mb) * 17 + (r2 & 15);
        float s = blds[r2] + ((pc[pbase] + pc[pbase + 272]) +
                              (pc[pbase + 544] + pc[pbase + 816]));
        glds[mb * 33 + r2] = s;
      }
      __syncthreads();
      if (tid < 128) {  // pointwise LSTM
        const int bbl = tid >> 3, hl = tid & 7;
        const int bb2 = bg * 16 + bbl, hu = rg * 8 + hl;
        const float gi = glds[bbl * 33 + hl],      gf = glds[bbl * 33 + 8 + hl];
        const float gg = glds[bbl * 33 + 16 + hl], go = glds[bbl * 33 + 24 + hl];
        const float cold = cbuf[bb2 * HID + hu];  // block-private: plain cached ok
        const float cn = fast_sig(gf) * cold + fast_sig(gi) * fast_tanh(gg);
        const float hn = fast_sig(go) * fast_tanh(cn);
        cbuf[bb2 * HID + hu] = cn;
        ast(&hnext[bb2 * HID + hu], hn);            // fp32 for PA
        const float ho = __shfl_xor(hn, 1, 64);     // bf16 pair for next PB
        if ((hl & 1) == 0)
          astu(hpk + (size_t)((t + 1) & 1) * B * 256 + bb2 * 256 + rg * 4 + (hl >> 1),
               f2bf(hn) | (f2bf(ho) << 16));
      }
    }
    ++seq; gridbar(flags, seq, bid, tid);
  }

  // ---------------- epilogue: out(127) from h_128 (hbuf slot 0) ----------------
  {
    hsh[tid] = ald(hbuf + (size_t)b * HID + tid);
    __syncthreads();
    if (tid < 128) {
      const int o = qt * 16 + (tid >> 3), c = tid & 7;
      const unsigned short* wr = Wfc2 + (size_t)o * HID;
      float oa = 0.f;
      #pragma unroll
      for (int j = 0; j < 8; ++j) {
        const int jj = c * 64 + ((j + c) & 7) * 8;
        uint4 w8 = *(const uint4*)(wr + jj);
        const float* hp = &hsh[jj];
        oa = fmaf(bflo(w8.x), hp[0], oa); oa = fmaf(bfhi(w8.x), hp[1], oa);
        oa = fmaf(bflo(w8.y), hp[2], oa); oa = fmaf(bfhi(w8.y), hp[3], oa);
        oa = fmaf(bflo(w8.z), hp[4], oa); oa = fmaf(bfhi(w8.z), hp[5], oa);
        oa = fmaf(bflo(w8.w), hp[6], oa); oa = fmaf(bfhi(w8.w), hp[7], oa);
      }
      oa += __shfl_xor(oa, 1, 64); oa += __shfl_xor(oa, 2, 64);
      oa += __shfl_xor(oa, 4, 64);
      if (c == 0) out[((size_t)b * T + 127) * OUTD + o] = oa + bfc[o];
    }
  }
}

extern "C" void kernel_launch(void* const* d_in, const int* in_sizes, int n_in,
                              void* d_out, int out_size, void* d_ws, size_t ws_size,
                              hipStream_t stream) {
  const float* x   = (const float*)d_in[0];
  const float* enc = (const float*)d_in[1];
  const float* Wq  = (const float*)d_in[2];
  const float* Wk  = (const float*)d_in[3];
  const float* v   = (const float*)d_in[4];
  const float* Wih = (const float*)d_in[5];
  const float* Whh = (const float*)d_in[6];
  const float* bih = (const float*)d_in[7];
  const float* bhh = (const float*)d_in[8];
  const float* Wfc = (const float*)d_in[9];
  const float* bfc = (const float*)d_in[10];

  // ws layout (~28.4 MB)
  unsigned short* enc2  = (unsigned short*)d_ws;          // B*TE*HID
  unsigned short* keys2 = enc2 + (size_t)B * TE * HID;    // B*TE*ATTN
  unsigned short* Wq2   = keys2 + (size_t)B * TE * ATTN;  // ATTN*HID
  unsigned short* Wfc2  = Wq2 + ATTN * HID;               // OUTD*HID
  float* hbuf = (float*)(Wfc2 + OUTD * HID);  // 2*B*HID fp32
  float* cbuf = hbuf + 2 * B * HID;           // B*HID
  float* ctxb = cbuf + B * HID;               // 2*B*HID (dbuf accumulators)
  float* denb = ctxb + 2 * B * HID;           // 2*B
  unsigned* hpk = (unsigned*)(denb + 2 * B);  // 2*B*256 packed bf16 h (dbuf)
  int* flags = (int*)(hpk + 2 * B * 256);     // 256
  unsigned* x2pk = (unsigned*)(flags + 256);  // B*T*32 packed bf16 x

  // zero hbuf|cbuf|ctxb|denb|hpk|flags (contiguous) every call
  const size_t zero_units = 2 * B * HID + B * HID + 2 * B * HID + 2 * B +
                            2 * B * 256 + 256;
  hipMemsetAsync(hbuf, 0, zero_units * 4, stream);

  cvt_kernel<<<dim3(512), dim3(256), 0, stream>>>(enc, enc2, B * TE * HID);
  cvt_kernel<<<dim3(64), dim3(256), 0, stream>>>(Wq, Wq2, ATTN * HID);
  cvt_kernel<<<dim3(32), dim3(256), 0, stream>>>(Wfc, Wfc2, OUTD * HID);
  pack2_kernel<<<dim3(128), dim3(256), 0, stream>>>(x, x2pk, B * T * 32);
  keys_kernel<<<dim3(1024), dim3(256), 0, stream>>>(enc, Wk, keys2);
  main_kernel<<<dim3(G), dim3(BS), 0, stream>>>(
      v, Wih, Whh, bih, bhh, bfc, enc2, keys2, Wq2, Wfc2, x2pk,
      hbuf, cbuf, ctxb, denb, hpk, flags, (float*)d_out);
}